// Round 1
// baseline (4057.854 us; speedup 1.0000x reference)
//
#include <hip/hip_runtime.h>
#include <cstdint>
#include <cstddef>

#define DEVI __device__ __forceinline__

static constexpr int HW = 65536;          // 256*256
static constexpr float PTOTF = 524288.0f; // 8*256*256

DEVI unsigned short f2bf(float f) {
  unsigned int x = __float_as_uint(f);
  x += 0x7fffu + ((x >> 16) & 1u);
  return (unsigned short)(x >> 16);
}
DEVI float celuf(float v) { return v > 0.0f ? v : expm1f(v); }

DEVI void unpack8(const uint4 u, float* v) {
  v[0] = __uint_as_float(u.x << 16); v[1] = __uint_as_float(u.x & 0xffff0000u);
  v[2] = __uint_as_float(u.y << 16); v[3] = __uint_as_float(u.y & 0xffff0000u);
  v[4] = __uint_as_float(u.z << 16); v[5] = __uint_as_float(u.z & 0xffff0000u);
  v[6] = __uint_as_float(u.w << 16); v[7] = __uint_as_float(u.w & 0xffff0000u);
}

// ---- weight transform: src [OC][IC][3][3] -> dst [9][ICP][OCP] (zero-padded)
__global__ void k_wt(const float* __restrict__ w, float* __restrict__ dst,
                     int OC, int IC, int ICP, int OCP) {
  const int tot = 9 * ICP * OCP;
  for (int idx = blockIdx.x * blockDim.x + threadIdx.x; idx < tot;
       idx += gridDim.x * blockDim.x) {
    const int tap = idx / (ICP * OCP);
    const int r = idx - tap * (ICP * OCP);
    const int ic = r / OCP, oc = r - ic * OCP;
    dst[idx] = (ic < IC && oc < OC) ? w[(oc * IC + ic) * 9 + tap] : 0.0f;
  }
}

// ---- instance norm stats: one block per (n,c); mean + unbiased rstd
__global__ __launch_bounds__(256)
void k_inorm(const float* __restrict__ x, float* __restrict__ ms) {
  __shared__ float s1[256], s2[256];
  const int b = blockIdx.x;
  const float4* p = (const float4*)(x + (size_t)b * HW);
  float sum = 0.f, sq = 0.f;
  for (int j = threadIdx.x; j < HW / 4; j += 256) {
    const float4 v = p[j];
    sum += v.x + v.y + v.z + v.w;
    sq  += v.x * v.x + v.y * v.y + v.z * v.z + v.w * v.w;
  }
  s1[threadIdx.x] = sum; s2[threadIdx.x] = sq;
  __syncthreads();
  for (int s = 128; s > 0; s >>= 1) {
    if ((int)threadIdx.x < s) {
      s1[threadIdx.x] += s1[threadIdx.x + s];
      s2[threadIdx.x] += s2[threadIdx.x + s];
    }
    __syncthreads();
  }
  if (threadIdx.x == 0) {
    const float m = s1[0] * (1.0f / HW);
    const float var = (s2[0] - s1[0] * s1[0] * (1.0f / HW)) * (1.0f / (HW - 1));
    ms[2 * b] = m;
    ms[2 * b + 1] = rsqrtf(var);
  }
}

// ---- generic 3x3 conv, NHWC bf16 in/out (raw pre-BN output, no bias needed).
// MODE 0: conv1 — build 8ch input on the fly from x (NCHW fp32) + instance norm
// MODE 1: 64ch input, identity transform
// MODE 2: 64ch input, per-channel BN affine + CELU applied at staging
// Block: 64 output px (one row segment) x 64 oc. 256 threads: t&15 -> oc quad,
// t>>4 -> px quad. LDS input stride 9 (conflict-free), weights [9][8][64].
template<int NCHUNK, int MODE>
__global__ __launch_bounds__(256)
void k_conv(const unsigned short* __restrict__ in, const float* __restrict__ x,
            const float* __restrict__ ms, const float* __restrict__ bnp,
            const float* __restrict__ wt, unsigned short* __restrict__ out) {
  __shared__ float in_s[3 * 66 * 9];
  __shared__ float w_s[9 * 8 * 64];
  __shared__ float s_sc[64], s_sh[64];

  const int t = threadIdx.x;
  const int b = blockIdx.x;
  const int n = b >> 10;
  const int h = (b >> 2) & 255;
  const int w0 = (b & 3) << 6;

  if (MODE == 2 && t < 64) { s_sc[t] = bnp[t]; s_sh[t] = bnp[64 + t]; }
  float m0 = 0, r0 = 0, m1 = 0, r1 = 0, m2 = 0, r2 = 0;
  if (MODE == 0) {
    m0 = ms[6 * n + 0]; r0 = ms[6 * n + 1];
    m1 = ms[6 * n + 2]; r1 = ms[6 * n + 3];
    m2 = ms[6 * n + 4]; r2 = ms[6 * n + 5];
  }
  if (MODE == 2) __syncthreads();

  const int oc0 = (t & 15) * 4;
  const int px0 = (t >> 4) * 4;
  float acc[4][4] = {{0.f}};

  for (int ch = 0; ch < NCHUNK; ++ch) {
    const int ic0 = ch * 8;
    {  // stage weights for this ic chunk: [9][8][64] floats
      constexpr int ICT = NCHUNK * 8;
      const float4* wsrc = (const float4*)wt;
      for (int j4 = t; j4 < 1152; j4 += 256) {
        const int tap = j4 >> 7, r4 = j4 & 127;
        ((float4*)w_s)[j4] = wsrc[tap * (ICT * 16) + ic0 * 16 + r4];
      }
    }
    if (t < 198) {  // stage input tile [3][66][stride 9]
      const int dh = t / 66, px = t - dh * 66;
      const int gh = h + dh - 1, gw = w0 + px - 1;
      const bool ok = ((unsigned)gh < 256u) && ((unsigned)gw < 256u);
      float v[8];
      if (MODE == 0) {
        if (ok) {
          const float* xp = x + (size_t)n * 3 * HW + gh * 256 + gw;
          const float a0 = xp[0], a1 = xp[HW], a2 = xp[2 * HW];
          v[0] = a0; v[1] = a1; v[2] = a2;
          v[3] = (a0 - m0) * r0; v[4] = (a1 - m1) * r1; v[5] = (a2 - m2) * r2;
          v[6] = 0.f; v[7] = 0.f;
        } else {
#pragma unroll
          for (int q = 0; q < 8; ++q) v[q] = 0.f;
        }
      } else {
        if (ok) {
          const uint4 u = *(const uint4*)(in + ((((size_t)n * 256 + gh) * 256 + gw) * 64 + ic0));
          unpack8(u, v);
          if (MODE == 2) {
#pragma unroll
            for (int q = 0; q < 8; ++q) v[q] = celuf(v[q] * s_sc[ic0 + q] + s_sh[ic0 + q]);
          }
        } else {
#pragma unroll
          for (int q = 0; q < 8; ++q) v[q] = 0.f;
        }
      }
      float* d = &in_s[(dh * 66 + px) * 9];
#pragma unroll
      for (int q = 0; q < 8; ++q) d[q] = v[q];
    }
    __syncthreads();
#pragma unroll
    for (int i = 0; i < 8; ++i) {
      float xv[3][6];
#pragma unroll
      for (int dh = 0; dh < 3; ++dh) {
#pragma unroll
        for (int j = 0; j < 6; ++j)
          xv[dh][j] = in_s[(dh * 66 + px0 + j) * 9 + i];
      }
#pragma unroll
      for (int dh = 0; dh < 3; ++dh) {
#pragma unroll
        for (int dw = 0; dw < 3; ++dw) {
          const float4 wv = *(const float4*)&w_s[((dh * 3 + dw) * 8 + i) * 64 + oc0];
#pragma unroll
          for (int p = 0; p < 4; ++p) {
            const float xin = xv[dh][p + dw];
            acc[p][0] += xin * wv.x;
            acc[p][1] += xin * wv.y;
            acc[p][2] += xin * wv.z;
            acc[p][3] += xin * wv.w;
          }
        }
      }
    }
    __syncthreads();
  }

  unsigned short* ob = out + (((size_t)n * 256 + h) * 256 + w0) * 64;
#pragma unroll
  for (int p = 0; p < 4; ++p) {
    ushort4 o;
    o.x = f2bf(acc[p][0]); o.y = f2bf(acc[p][1]);
    o.z = f2bf(acc[p][2]); o.w = f2bf(acc[p][3]);
    *(ushort4*)(ob + (size_t)(px0 + p) * 64 + oc0) = o;
  }
}

// ---- BN stats pass 1: per-block partial (sum, sumsq) per channel. 1024 blocks x 512 px.
__global__ __launch_bounds__(256)
void k_bnstats(const unsigned short* __restrict__ y, float* __restrict__ psum,
               float* __restrict__ psq) {
  __shared__ float ls[256], lq[256];
  const int b = blockIdx.x;
  const int t = threadIdx.x;
  const int c = t & 63, sub = t >> 6;
  float sum = 0.f, sq = 0.f;
  const size_t base = (size_t)b * 512 * 64;
  for (int j = sub; j < 512; j += 4) {
    const float v = __uint_as_float(((unsigned int)y[base + (size_t)j * 64 + c]) << 16);
    sum += v; sq += v * v;
  }
  ls[t] = sum; lq[t] = sq;
  __syncthreads();
  if (t < 128) { ls[t] += ls[t + 128]; lq[t] += lq[t + 128]; }
  __syncthreads();
  if (t < 64) {
    psum[(size_t)b * 64 + t] = ls[t] + ls[t + 64];
    psq[(size_t)b * 64 + t]  = lq[t] + lq[t + 64];
  }
}

// ---- BN stats pass 2: reduce 1024 partials, emit per-channel scale/shift
__global__ __launch_bounds__(256)
void k_bnfin(const float* __restrict__ psum, const float* __restrict__ psq,
             const float* __restrict__ g, const float* __restrict__ be,
             float* __restrict__ bnp) {
  __shared__ float s1[256], s2[256];
  const int t = threadIdx.x;
  const int c = t & 63, sub = t >> 6;
  float s = 0.f, q = 0.f;
  for (int b = sub; b < 1024; b += 4) {
    s += psum[(size_t)b * 64 + c];
    q += psq[(size_t)b * 64 + c];
  }
  s1[t] = s; s2[t] = q;
  __syncthreads();
  if (t < 64) {
    s = s1[t] + s1[t + 64] + s1[t + 128] + s1[t + 192];
    q = s2[t] + s2[t + 64] + s2[t + 128] + s2[t + 192];
    const float m = s / PTOTF;
    const float var = q / PTOTF - m * m;
    const float sc = g[t] * rsqrtf(var + 1e-5f);
    bnp[t] = sc;
    bnp[64 + t] = be[t] - m * sc;
  }
}

// ---- elementwise: a = celu(y*scale+shift) [+ a]   (RES=1 for residual add)
template<int RES>
__global__ __launch_bounds__(256)
void k_apply(const unsigned short* __restrict__ y, const float* __restrict__ bnp,
             unsigned short* __restrict__ a) {
  const size_t i = ((size_t)blockIdx.x * 256 + threadIdx.x) * 8;
  const int c0 = (int)(i & 63);
  float v[8];
  unpack8(*(const uint4*)(y + i), v);
  const float4 sa = *(const float4*)(bnp + c0);
  const float4 sb = *(const float4*)(bnp + c0 + 4);
  const float4 ha = *(const float4*)(bnp + 64 + c0);
  const float4 hb = *(const float4*)(bnp + 64 + c0 + 4);
  const float sc[8] = {sa.x, sa.y, sa.z, sa.w, sb.x, sb.y, sb.z, sb.w};
  const float sh[8] = {ha.x, ha.y, ha.z, ha.w, hb.x, hb.y, hb.z, hb.w};
  float r[8];
#pragma unroll
  for (int q = 0; q < 8; ++q) r[q] = celuf(v[q] * sc[q] + sh[q]);
  if (RES) {
    float av[8];
    unpack8(*(const uint4*)(a + i), av);
#pragma unroll
    for (int q = 0; q < 8; ++q) r[q] += av[q];
  }
  uint4 o;
  o.x = (unsigned)f2bf(r[0]) | ((unsigned)f2bf(r[1]) << 16);
  o.y = (unsigned)f2bf(r[2]) | ((unsigned)f2bf(r[3]) << 16);
  o.z = (unsigned)f2bf(r[4]) | ((unsigned)f2bf(r[5]) << 16);
  o.w = (unsigned)f2bf(r[6]) | ((unsigned)f2bf(r[7]) << 16);
  *(uint4*)(a + i) = o;
}

// ---- last conv 64->3 + bias + celu + x, NCHW fp32 output
__global__ __launch_bounds__(256)
void k_last(const unsigned short* __restrict__ a, const float* __restrict__ x,
            const float* __restrict__ wl, const float* __restrict__ b2,
            float* __restrict__ outp) {
  __shared__ float wsm[2304];  // [9][64][4]
  for (int j = threadIdx.x; j < 2304; j += 256) wsm[j] = wl[j];
  __syncthreads();
  const int px = blockIdx.x * 256 + threadIdx.x;
  const int n = px >> 16, rem = px & 65535, h = rem >> 8, w = rem & 255;
  float a0 = 0.f, a1 = 0.f, a2 = 0.f;
  for (int dh = 0; dh < 3; ++dh) {
    const int gh = h + dh - 1;
    if ((unsigned)gh >= 256u) continue;
    for (int dw = 0; dw < 3; ++dw) {
      const int gw = w + dw - 1;
      if ((unsigned)gw >= 256u) continue;
      const uint4* p = (const uint4*)(a + (((size_t)n * 256 + gh) * 256 + gw) * 64);
      const float* wt = &wsm[(dh * 3 + dw) * 256];
#pragma unroll
      for (int iv = 0; iv < 8; ++iv) {
        float v[8];
        unpack8(p[iv], v);
#pragma unroll
        for (int q = 0; q < 8; ++q) {
          const float* wr = &wt[(iv * 8 + q) * 4];
          a0 += v[q] * wr[0];
          a1 += v[q] * wr[1];
          a2 += v[q] * wr[2];
        }
      }
    }
  }
  const size_t ob = (size_t)n * 3 * HW + ((size_t)h << 8) + w;
  outp[ob]          = celuf(a0 + b2[0]) + x[ob];
  outp[ob + HW]     = celuf(a1 + b2[1]) + x[ob + HW];
  outp[ob + 2 * HW] = celuf(a2 + b2[2]) + x[ob + 2 * HW];
}

extern "C" void kernel_launch(void* const* d_in, const int* in_sizes, int n_in,
                              void* d_out, int out_size, void* d_ws, size_t ws_size,
                              hipStream_t stream) {
  const float* x   = (const float*)d_in[0];
  const float* w1  = (const float*)d_in[1];
  // d_in[2] = b1 (cancels under BN)
  const float* g1  = (const float*)d_in[3];
  const float* be1 = (const float*)d_in[4];
  const float* bw  = (const float*)d_in[5];
  // d_in[6] = bb (cancels under BN)
  const float* bg  = (const float*)d_in[7];
  const float* bbe = (const float*)d_in[8];
  const float* w2  = (const float*)d_in[9];
  const float* b2  = (const float*)d_in[10];
  float* out = (float*)d_out;

  // workspace layout (256B aligned)
  size_t off = 0;
  auto alloc = [&](size_t bytes) {
    size_t cur = off;
    off += (bytes + 255) & ~(size_t)255;
    return cur;
  };
  const size_t oA   = alloc((size_t)33554432 * 2);  // bufA bf16 NHWC
  const size_t oB   = alloc((size_t)33554432 * 2);  // bufB
  const size_t oC   = alloc((size_t)33554432 * 2);  // bufC
  const size_t oW1  = alloc(4608 * 4);              // conv1 wt [9][8][64]
  const size_t oWM  = alloc((size_t)6 * 36864 * 4); // 6 main wt [9][64][64]
  const size_t oWL  = alloc(2304 * 4);              // last wt [9][64][4]
  const size_t oMS  = alloc(48 * 4);                // instnorm mean/rstd
  const size_t oBNP = alloc(7 * 128 * 4);           // 7 bn (scale,shift) slots
  const size_t oPS  = alloc((size_t)1024 * 64 * 4); // partial sums
  const size_t oPQ  = alloc((size_t)1024 * 64 * 4); // partial sumsq
  if (off > ws_size) return;  // workspace too small — fail loudly

  char* wsb = (char*)d_ws;
  unsigned short* bufA = (unsigned short*)(wsb + oA);
  unsigned short* bufB = (unsigned short*)(wsb + oB);
  unsigned short* bufC = (unsigned short*)(wsb + oC);
  float* wt1 = (float*)(wsb + oW1);
  float* wtm = (float*)(wsb + oWM);
  float* wtl = (float*)(wsb + oWL);
  float* ms  = (float*)(wsb + oMS);
  float* bnp = (float*)(wsb + oBNP);
  float* psum = (float*)(wsb + oPS);
  float* psq  = (float*)(wsb + oPQ);

  // weight transforms
  k_wt<<<8, 256, 0, stream>>>(w1, wt1, 64, 6, 8, 64);
  for (int i = 0; i < 6; ++i)
    k_wt<<<64, 256, 0, stream>>>(bw + (size_t)i * 64 * 64 * 9, wtm + (size_t)i * 36864, 64, 64, 64, 64);
  k_wt<<<8, 256, 0, stream>>>(w2, wtl, 3, 64, 64, 4);

  // instance norm stats
  k_inorm<<<24, 256, 0, stream>>>(x, ms);

  // conv1 (6->64): raw output to bufB
  k_conv<1, 0><<<8192, 256, 0, stream>>>(nullptr, x, ms, nullptr, wt1, bufB);
  k_bnstats<<<1024, 256, 0, stream>>>(bufB, psum, psq);
  k_bnfin<<<1, 256, 0, stream>>>(psum, psq, g1, be1, bnp + 0 * 128);
  k_apply<0><<<16384, 256, 0, stream>>>(bufB, bnp + 0 * 128, bufA);  // bufA = activation

  for (int i = 0; i < 3; ++i) {
    const int s1 = 1 + 2 * i, s2 = 2 + 2 * i;
    // convA: activation -> raw bufB
    k_conv<8, 1><<<8192, 256, 0, stream>>>(bufA, nullptr, nullptr, nullptr,
                                           wtm + (size_t)(2 * i) * 36864, bufB);
    k_bnstats<<<1024, 256, 0, stream>>>(bufB, psum, psq);
    k_bnfin<<<1, 256, 0, stream>>>(psum, psq, bg + (size_t)(2 * i) * 64,
                                   bbe + (size_t)(2 * i) * 64, bnp + (size_t)s1 * 128);
    // convB: BN+CELU(bufB) -> raw bufC
    k_conv<8, 2><<<8192, 256, 0, stream>>>(bufB, nullptr, nullptr, bnp + (size_t)s1 * 128,
                                           wtm + (size_t)(2 * i + 1) * 36864, bufC);
    k_bnstats<<<1024, 256, 0, stream>>>(bufC, psum, psq);
    k_bnfin<<<1, 256, 0, stream>>>(psum, psq, bg + (size_t)(2 * i + 1) * 64,
                                   bbe + (size_t)(2 * i + 1) * 64, bnp + (size_t)s2 * 128);
    // residual: bufA = celu(bn(bufC)) + bufA
    k_apply<1><<<16384, 256, 0, stream>>>(bufC, bnp + (size_t)s2 * 128, bufA);
  }

  // last conv 64->3 + bias + celu + x
  k_last<<<2048, 256, 0, stream>>>(bufA, x, wtl, b2, out);
}